// Round 4
// baseline (156.526 us; speedup 1.0000x reference)
//
#include <hip/hip_runtime.h>

typedef unsigned short u16;
typedef __attribute__((ext_vector_type(8))) short short8;
typedef __attribute__((ext_vector_type(4))) float f32x4;

#define X0    (-6.0f)
#define GH    (12.0f / 256.0f)     // grid spacing h = 0.046875
#define LOG2E 1.44269504089f

__device__ __forceinline__ u16 f2bf(float x) {
    union { float f; unsigned int u; } v; v.f = x;
    unsigned int r = (v.u + 0x7fffu + ((v.u >> 16) & 1u)) >> 16;
    return (u16)r;
}
__device__ __forceinline__ unsigned int pk(u16 a, u16 b) {
    return (unsigned int)a | ((unsigned int)b << 16);
}
__device__ __forceinline__ uint4 cvt8u(float4 lo, float4 hi) {
    return make_uint4(pk(f2bf(lo.x), f2bf(lo.y)), pk(f2bf(lo.z), f2bf(lo.w)),
                      pk(f2bf(hi.x), f2bf(hi.y)), pk(f2bf(hi.z), f2bf(hi.w)));
}

// A: blocks [0,1024): value fp32 -> Vb bf16 (16 MB), streaming.
//    blocks [1024,1280): build Wt[b][j][s] bf16 (8 MB) + zero Hf (2 MB).
__global__ __launch_bounds__(256) void prep_kernel(
    const float* __restrict__ key, const float* __restrict__ value,
    u16* __restrict__ Vb, u16* __restrict__ Wt, float* __restrict__ Hf)
{
    __shared__ int   jl[64];
    __shared__ float fl[64];
    const int tid = threadIdx.x;

    if (blockIdx.x < 1024) {
        const size_t base = ((size_t)blockIdx.x * 256 + tid) * 32;
        const float* src = value + base;
        u16* dst = Vb + base;
        #pragma unroll
        for (int r = 0; r < 4; ++r) {
            float4 lo = *(const float4*)(src + r * 8);
            float4 hi = *(const float4*)(src + r * 8 + 4);
            *(uint4*)(dst + r * 8) = cvt8u(lo, hi);
        }
        return;
    }

    const int blk = blockIdx.x - 1024;       // 0..255
    const int b   = blk >> 6;
    const int s0  = (blk & 63) << 6;

    if (tid < 64) {
        float k = key[b * 4096 + s0 + tid];
        float u = (k - X0) * (256.0f / 12.0f);
        int j = (int)floorf(u);
        j = j < 0 ? 0 : (j > 254 ? 254 : j);
        float f = u - (float)j;
        f = f < 0.0f ? 0.0f : (f > 1.0f ? 1.0f : f);
        jl[tid] = j; fl[tid] = f;
    }
    {   // zero Hf: 524288 floats / (256 blk * 256 thr) = 8 each
        float4 z = make_float4(0.f, 0.f, 0.f, 0.f);
        float* p = Hf + ((size_t)blk * 256 + tid) * 8;
        *(float4*)p = z; *(float4*)(p + 4) = z;
    }
    __syncthreads();

    u16 e[64];
    #pragma unroll
    for (int i = 0; i < 64; ++i) {
        int j = jl[i]; float f = fl[i];
        float w = (j == tid) ? (1.0f - f) : ((j + 1 == tid) ? f : 0.0f);
        e[i] = f2bf(w);
    }
    u16* row = Wt + ((size_t)(b * 256 + tid)) * 4096 + s0;
    #pragma unroll
    for (int r = 0; r < 8; ++r) {
        uint4 o = make_uint4(pk(e[r*8+0], e[r*8+1]), pk(e[r*8+2], e[r*8+3]),
                             pk(e[r*8+4], e[r*8+5]), pk(e[r*8+6], e[r*8+7]));
        *(uint4*)(row + r * 8) = o;
    }
}

// B: Hf[v][j] += sum_s Vb[v][s] * Wt[j][s]. bf16 MFMA, M=512 N=256 K=4096,
// 16-way k-split (512 blocks, 2/CU), 2-deep register prefetch, native f32 atomics.
__global__ __launch_bounds__(256, 2) void hgemm_kernel(
    const u16* __restrict__ Vb, const u16* __restrict__ Wt,
    float* __restrict__ Hf)
{
    const int tid   = threadIdx.x;
    const int j0    = blockIdx.x << 7;
    const int v0    = blockIdx.y << 7;
    const int b     = blockIdx.z >> 4;
    const int ks    = blockIdx.z & 15;
    const int kbase = ks << 8;               // 256-wide K chunk
    const int lane  = tid & 63;
    const int wave  = tid >> 6;
    const int wv    = (wave & 1) << 6;
    const int wj    = (wave >> 1) << 6;
    const int m15   = lane & 15;
    const int kq    = lane >> 4;

    f32x4 acc[4][4];
    for (int i = 0; i < 4; ++i)
        for (int j = 0; j < 4; ++j)
            acc[i][j] = (f32x4){0.f, 0.f, 0.f, 0.f};

    const u16* ap[4];
    const u16* bp[4];
    for (int i = 0; i < 4; ++i) {
        ap[i] = Vb + (size_t)(b * 512 + v0 + wv + i * 16 + m15) * 4096 + kbase + kq * 8;
        bp[i] = Wt + (size_t)(b * 256 + j0 + wj + i * 16 + m15) * 4096 + kbase + kq * 8;
    }

    union U { short8 s; uint4 u; };
    uint4 abuf[2][4], wbuf[2][4];
    for (int i = 0; i < 4; ++i) {
        abuf[0][i] = *(const uint4*)(ap[i]);
        wbuf[0][i] = *(const uint4*)(bp[i]);
    }

    for (int kk = 0; kk < 8; ++kk) {
        const int cur = kk & 1;
        if (kk < 7) {
            const int ko = (kk + 1) << 5;
            for (int i = 0; i < 4; ++i) {
                abuf[cur ^ 1][i] = *(const uint4*)(ap[i] + ko);
                wbuf[cur ^ 1][i] = *(const uint4*)(bp[i] + ko);
            }
        }
        for (int mi = 0; mi < 4; ++mi)
            for (int ni = 0; ni < 4; ++ni) {
                U a, w; a.u = abuf[cur][mi]; w.u = wbuf[cur][ni];
                acc[mi][ni] = __builtin_amdgcn_mfma_f32_16x16x32_bf16(
                    a.s, w.s, acc[mi][ni], 0, 0, 0);
            }
    }

    for (int mi = 0; mi < 4; ++mi)
        for (int ni = 0; ni < 4; ++ni) {
            float* base = Hf + (size_t)(b * 512 + v0 + wv + mi * 16 + (kq << 2)) * 256
                             + j0 + wj + ni * 16 + m15;
            for (int r = 0; r < 4; ++r)
                unsafeAtomicAdd(base + (size_t)r * 256, acc[mi][ni][r]);
        }
}

// C: Hf fp32 -> Hbf bf16 (once).
__global__ __launch_bounds__(256) void hred_kernel(
    const float* __restrict__ Hf, u16* __restrict__ Hbf)
{
    const size_t gid = (size_t)blockIdx.x * 256 + threadIdx.x;
    const float* p = Hf + gid * 8;
    float4 lo = *(const float4*)p;
    float4 hi = *(const float4*)(p + 4);
    *(uint4*)(Hbf + gid * 8) = cvt8u(lo, hi);
}

// D: out[b][t][v] = sum_k G(q_t, x_k) * H[v][k].  No LDS, no barriers.
// A-frags prefetched from L2-resident Hbf; Gaussian B-frags on the fly.
__global__ __launch_bounds__(256) void gemm_kernel(
    const float* __restrict__ query, const float* __restrict__ log_scale,
    const u16* __restrict__ Hbf, float* __restrict__ out)
{
    const int tid  = threadIdx.x;
    const int v0   = blockIdx.x << 7;
    const int t0   = blockIdx.y << 7;
    const int b    = blockIdx.z;
    const int lane = tid & 63;
    const int wave = tid >> 6;
    const int wv   = (wave & 1) << 6;
    const int wt   = (wave >> 1) << 6;
    const int m15  = lane & 15;
    const int kq   = lane >> 4;

    const float c2 = -0.5f * LOG2E * exp2f(-2.0f * LOG2E * log_scale[0]);
    float q[4];
    for (int ni = 0; ni < 4; ++ni)
        q[ni] = query[b * 4096 + t0 + wt + ni * 16 + m15];

    const u16* hp[4];
    for (int i = 0; i < 4; ++i)
        hp[i] = Hbf + (size_t)(b * 512 + v0 + wv + i * 16 + m15) * 256 + kq * 8;

    f32x4 acc[4][4];
    for (int i = 0; i < 4; ++i)
        for (int j = 0; j < 4; ++j)
            acc[i][j] = (f32x4){0.f, 0.f, 0.f, 0.f};

    union U { short8 s; uint4 u; };
    uint4 abuf[2][4];
    for (int i = 0; i < 4; ++i) abuf[0][i] = *(const uint4*)(hp[i]);

    for (int ks = 0; ks < 8; ++ks) {
        const int cur = ks & 1;
        if (ks < 7) {
            const int ko = (ks + 1) << 5;
            for (int i = 0; i < 4; ++i)
                abuf[cur ^ 1][i] = *(const uint4*)(hp[i] + ko);
        }

        short8 bfr[4];
        const float xb = X0 + GH * (float)((ks << 5) + kq * 8);
        for (int ni = 0; ni < 4; ++ni) {
            short8 e;
            #pragma unroll
            for (int j = 0; j < 8; ++j) {
                float d = q[ni] - (xb + GH * (float)j);
                e[j] = (short)f2bf(exp2f(c2 * d * d));
            }
            bfr[ni] = e;
        }

        for (int mi = 0; mi < 4; ++mi)
            for (int ni = 0; ni < 4; ++ni) {
                U a; a.u = abuf[cur][mi];
                acc[mi][ni] = __builtin_amdgcn_mfma_f32_16x16x32_bf16(
                    a.s, bfr[ni], acc[mi][ni], 0, 0, 0);
            }
    }

    for (int mi = 0; mi < 4; ++mi)
        for (int ni = 0; ni < 4; ++ni) {
            int t = t0 + wt + ni * 16 + m15;
            float* o = out + (size_t)(b * 4096 + t) * 512
                           + v0 + wv + mi * 16 + (kq << 2);
            *(f32x4*)o = acc[mi][ni];
        }
}

extern "C" void kernel_launch(void* const* d_in, const int* in_sizes, int n_in,
                              void* d_out, int out_size, void* d_ws, size_t ws_size,
                              hipStream_t stream)
{
    const float* query = (const float*)d_in[0];   // [4,4096,1]
    const float* key   = (const float*)d_in[1];   // [4,4096,1]
    const float* value = (const float*)d_in[2];   // [4,512,4096]
    float* out = (float*)d_out;                   // [4,4096,512]
    const float* lsc = (const float*)d_in[3];

    char* ws = (char*)d_ws;
    u16*   Vb  = (u16*)ws;                                   // 16 MB
    u16*   Wt  = (u16*)(ws + (size_t)16 * 1024 * 1024);      //  8 MB
    float* Hf  = (float*)(ws + (size_t)24 * 1024 * 1024);    //  2 MB
    u16*   Hbf = (u16*)(ws + (size_t)26 * 1024 * 1024);      //  1 MB

    prep_kernel<<<1280, 256, 0, stream>>>(key, value, Vb, Wt, Hf);
    hgemm_kernel<<<dim3(2, 4, 64), 256, 0, stream>>>(Vb, Wt, Hf);
    hred_kernel<<<256, 256, 0, stream>>>(Hf, Hbf);
    gemm_kernel<<<dim3(4, 32, 4), 256, 0, stream>>>(query, lsc, Hbf, out);
}